// Round 2
// baseline (126.090 us; speedup 1.0000x reference)
//
#include <hip/hip_runtime.h>

#define DIMS 64
#define KCB 512
#define OUT_Q 8388608   // 32*64*64*64
#define MAIN_WGS 1024

typedef float f32x4 __attribute__((ext_vector_type(4)));
typedef float f4    __attribute__((ext_vector_type(4)));
typedef short short8 __attribute__((ext_vector_type(8)));

// ws layout (bytes):
//   [0..4)      float   loss sum accumulator
//   [4..8)      uint    WG completion counter
//   [16..2064)  float   neg_half_c2[512]  (= -0.5*||c_k||^2)
//   [4096..69632) short bf16 codebook [512][64]

static __device__ __forceinline__ unsigned short f2bf(float f) {
    unsigned int u = __float_as_uint(f);
    unsigned int r = u + 0x7FFFu + ((u >> 16) & 1u);   // RNE
    return (unsigned short)(r >> 16);
}

__global__ void vq_prep(const float* __restrict__ cb, float* __restrict__ ws) {
    int t = blockIdx.x * blockDim.x + threadIdx.x;   // 0..511 = codebook row
    if (t == 0) { ws[0] = 0.0f; ((unsigned int*)ws)[1] = 0u; }
    if (t >= KCB) return;
    const f4* row = (const f4*)(cb + t * DIMS);
    unsigned int* dst = (unsigned int*)((char*)ws + 4096) + t * (DIMS / 2);
    float s = 0.0f;
#pragma unroll
    for (int i = 0; i < DIMS / 4; ++i) {
        f4 v = row[i];
        s += v[0]*v[0] + v[1]*v[1] + v[2]*v[2] + v[3]*v[3];
        unsigned int lo = ((unsigned int)f2bf(v[1]) << 16) | f2bf(v[0]);
        unsigned int hi = ((unsigned int)f2bf(v[3]) << 16) | f2bf(v[2]);
        dst[i * 2]     = lo;
        dst[i * 2 + 1] = hi;
    }
    ws[4 + t] = -0.5f * s;
}

__global__ __launch_bounds__(256, 4) void vq_main(const float* __restrict__ x,
                                                  const float* __restrict__ cb,
                                                  float* __restrict__ out,
                                                  float* __restrict__ ws) {
    const int lane = threadIdx.x & 63;
    const int wid  = threadIdx.x >> 6;
    const int iter = blockIdx.x * 4 + wid;        // 0..4095
    const long rowbase = (long)iter * 32;         // 32 x-rows per wave (2 tiles)
    const int r15 = lane & 15;
    const int g   = lane >> 4;

    // ---- A fragments: 2 tiles x 2 K-halves; lane holds A[row=r15][k=g*8+i(+32h)]
    short8 A0h0, A0h1, A1h0, A1h1;
    {
        const float* xa = x + (rowbase + r15) * DIMS + g * 8;
#pragma unroll
        for (int t = 0; t < 2; ++t) {
#pragma unroll
            for (int h = 0; h < 2; ++h) {
                const f4* p = (const f4*)(xa + t * 16 * DIMS + h * 32);
                f4 u0 = p[0], u1 = p[1];
                short8 fr;
                fr[0] = (short)f2bf(u0[0]); fr[1] = (short)f2bf(u0[1]);
                fr[2] = (short)f2bf(u0[2]); fr[3] = (short)f2bf(u0[3]);
                fr[4] = (short)f2bf(u1[0]); fr[5] = (short)f2bf(u1[1]);
                fr[6] = (short)f2bf(u1[2]); fr[7] = (short)f2bf(u1[3]);
                if (t == 0) { if (h == 0) A0h0 = fr; else A0h1 = fr; }
                else        { if (h == 0) A1h0 = fr; else A1h1 = fr; }
            }
        }
    }

    const short* cbbf = (const short*)((const char*)ws + 4096);
    const float* nhc2 = ws + 4;

    float bv[2][4];
    int   bk[2][4];
#pragma unroll
    for (int t = 0; t < 2; ++t)
#pragma unroll
        for (int j = 0; j < 4; ++j) { bv[t][j] = -3.4e38f; bk[t][j] = 0; }

#define LOADB(KT, B0, B1, IC)                                              \
    {                                                                      \
        int krow_ = ((KT) & 31) * 16 + r15;                                \
        IC = nhc2[krow_];                                                  \
        const short* bb_ = cbbf + krow_ * DIMS + g * 8;                    \
        B0 = *(const short8*)bb_;                                          \
        B1 = *(const short8*)(bb_ + 32);                                   \
    }

#define BODY(KT, B0, B1, IC)                                               \
    {                                                                      \
        const int krow_ = (KT) * 16 + r15;                                 \
        f32x4 init_ = {IC, IC, IC, IC};                                    \
        f32x4 acc0 = __builtin_amdgcn_mfma_f32_16x16x32_bf16(A0h0, B0, init_, 0, 0, 0); \
        acc0       = __builtin_amdgcn_mfma_f32_16x16x32_bf16(A0h1, B1, acc0,  0, 0, 0); \
        f32x4 acc1 = __builtin_amdgcn_mfma_f32_16x16x32_bf16(A1h0, B0, init_, 0, 0, 0); \
        acc1       = __builtin_amdgcn_mfma_f32_16x16x32_bf16(A1h1, B1, acc1,  0, 0, 0); \
        _Pragma("unroll")                                                  \
        for (int j = 0; j < 4; ++j) {                                      \
            if (acc0[j] > bv[0][j]) { bv[0][j] = acc0[j]; bk[0][j] = krow_; } \
            if (acc1[j] > bv[1][j]) { bv[1][j] = acc1[j]; bk[1][j] = krow_; } \
        }                                                                  \
    }

    // ---- score all 512 codebook entries: 32 k-tiles of 16, reg double-buffer
    short8 c0, c1, n0, n1;
    float icc, icn;
    LOADB(0, c0, c1, icc);
    for (int kt = 0; kt < 32; kt += 2) {
        LOADB(kt + 1, n0, n1, icn);       // prefetch odd tile
        BODY(kt, c0, c1, icc);            // consume even tile
        LOADB(kt + 2, c0, c1, icc);       // prefetch next even tile (wraps at 32)
        BODY(kt + 1, n0, n1, icn);        // consume odd tile
    }

    // ---- argmax reduce across the 16 lanes of each row-group (k dimension)
#pragma unroll
    for (int s = 0; s < 4; ++s) {
#pragma unroll
        for (int t = 0; t < 2; ++t) {
#pragma unroll
            for (int j = 0; j < 4; ++j) {
                float ov = __shfl_xor(bv[t][j], 1 << s, 64);
                int   ok = __shfl_xor(bk[t][j], 1 << s, 64);
                if (ov > bv[t][j] || (ov == bv[t][j] && ok < bk[t][j])) {
                    bv[t][j] = ov; bk[t][j] = ok;
                }
            }
        }
    }
    // now every lane in group g holds idx for rows g*4+j (j=0..3) of each tile

    // ---- epilogue: gather codebook rows (fp32), write out, accumulate loss
    const int orow = lane >> 2;        // 0..15: row within tile; orow>>2 == g
    const int cseg = lane & 3;         // 16-float column segment
    const int j2   = orow & 3;
    float lsum = 0.0f;
#pragma unroll
    for (int t = 0; t < 2; ++t) {
        int idx = bk[t][0];
        if (j2 == 1) idx = bk[t][1];
        if (j2 == 2) idx = bk[t][2];
        if (j2 == 3) idx = bk[t][3];
        const long row = rowbase + t * 16 + orow;
        const f4* cq = (const f4*)(cb + (long)idx * DIMS + cseg * 16);
        const f4* xr = (const f4*)(x + row * DIMS + cseg * 16);
        f4* op       = (f4*)(out + row * DIMS + cseg * 16);
#pragma unroll
        for (int u = 0; u < 4; ++u) {
            f4 q = cq[u];
            f4 xv = xr[u];
            op[u] = q;
            f4 d = q - xv;
            lsum += d[0]*d[0] + d[1]*d[1] + d[2]*d[2] + d[3]*d[3];
        }
    }

    // ---- loss: wave reduce -> WG reduce -> one atomic per WG -> last WG writes
#pragma unroll
    for (int s = 0; s < 6; ++s) lsum += __shfl_xor(lsum, 1 << s, 64);
    __shared__ float wsum[4];
    if (lane == 0) wsum[wid] = lsum;
    __syncthreads();
    if (threadIdx.x == 0) {
        float tot = wsum[0] + wsum[1] + wsum[2] + wsum[3];
        atomicAdd(ws, tot);
        __threadfence();
        unsigned int ticket = atomicAdd((unsigned int*)ws + 1, 1u);
        if (ticket == MAIN_WGS - 1) {
            float total = atomicAdd(ws, 0.0f);   // coherent read of final sum
            out[OUT_Q] = 1.25f * total / 8388608.0f;
        }
    }
}

extern "C" void kernel_launch(void* const* d_in, const int* in_sizes, int n_in,
                              void* d_out, int out_size, void* d_ws, size_t ws_size,
                              hipStream_t stream) {
    const float* x  = (const float*)d_in[0];
    const float* cb = (const float*)d_in[1];
    float* out = (float*)d_out;
    float* ws  = (float*)d_ws;
    vq_prep<<<2, 256, 0, stream>>>(cb, ws);
    vq_main<<<MAIN_WGS, 256, 0, stream>>>(x, cb, out, ws);
}

// Round 3
// 84.340 us; speedup vs baseline: 1.4950x; 1.4950x over previous
//
#include <hip/hip_runtime.h>

#define DIMS 64
#define KCB 512
#define OUT_Q 8388608   // 32*64*64*64
#define MAIN_WGS 1024

typedef float f32x4 __attribute__((ext_vector_type(4)));
typedef float f4    __attribute__((ext_vector_type(4)));
typedef short short8 __attribute__((ext_vector_type(8)));

// ws layout (bytes):
//   [0..4)        float  loss sum accumulator
//   [4..8)        uint   WG completion counter
//   [16..2064)    float  neg_half_c2[512]  (= -0.5*||c_k||^2)
//   [4096..69632) bf16   codebook packed in MFMA B-fragment order:
//                        byte = 4096 + kt*2048 + h*1024 + lane*16 + i*2
//                        holds cb[kt*16 + (lane&15)][h*32 + (lane>>4)*8 + i]

static __device__ __forceinline__ unsigned int f2bf(float f) {
    unsigned int u = __float_as_uint(f);
    unsigned int r = u + 0x7FFFu + ((u >> 16) & 1u);   // RNE
    return r >> 16;
}

__global__ void vq_prep(const float* __restrict__ cb, float* __restrict__ ws) {
    int t = blockIdx.x * blockDim.x + threadIdx.x;   // 0..4607
    if (t == 0) { ws[0] = 0.0f; ((unsigned int*)ws)[1] = 0u; }
    if (t < 4096) {
        // pack one 16-byte B-fragment slice
        int kt = t >> 7, rest = t & 127;
        int h = rest >> 6, l = rest & 63;
        int row = kt * 16 + (l & 15);
        int col = h * 32 + ((l >> 4) & 3) * 8;
        const f4* p = (const f4*)(cb + row * DIMS + col);
        f4 u0 = p[0], u1 = p[1];
        unsigned int* dst = (unsigned int*)((char*)ws + 4096 + kt * 2048 + h * 1024 + l * 16);
        dst[0] = (f2bf(u0[1]) << 16) | f2bf(u0[0]);
        dst[1] = (f2bf(u0[3]) << 16) | f2bf(u0[2]);
        dst[2] = (f2bf(u1[1]) << 16) | f2bf(u1[0]);
        dst[3] = (f2bf(u1[3]) << 16) | f2bf(u1[2]);
    } else if (t < 4096 + KCB) {
        int r = t - 4096;
        const f4* p = (const f4*)(cb + r * DIMS);
        float s = 0.0f;
#pragma unroll
        for (int i = 0; i < DIMS / 4; ++i) {
            f4 v = p[i];
            s += v[0]*v[0] + v[1]*v[1] + v[2]*v[2] + v[3]*v[3];
        }
        ws[4 + r] = -0.5f * s;
    }
}

__global__ __launch_bounds__(256) void vq_main(const float* __restrict__ x,
                                               const float* __restrict__ cb,
                                               float* __restrict__ out,
                                               float* __restrict__ ws) {
    const int lane = threadIdx.x & 63;
    const int wid  = threadIdx.x >> 6;
    const int iter = blockIdx.x * 4 + wid;        // 0..4095
    const long rowbase = (long)iter * 32;         // 32 x-rows per wave (2 tiles)
    const int r15 = lane & 15;
    const int g   = lane >> 4;

    // ---- A fragments (named, no arrays): lane holds A[row=r15][k=g*8+i(+32h)]
    short8 A00, A01, A10, A11;
    {
        const float* xa = x + (rowbase + r15) * DIMS + g * 8;
#define LOADA(FR, OFF)                                                     \
        {                                                                  \
            const f4* p_ = (const f4*)(xa + (OFF));                        \
            f4 u0_ = p_[0], u1_ = p_[1];                                   \
            short8 fr_;                                                    \
            fr_[0] = (short)f2bf(u0_[0]); fr_[1] = (short)f2bf(u0_[1]);    \
            fr_[2] = (short)f2bf(u0_[2]); fr_[3] = (short)f2bf(u0_[3]);    \
            fr_[4] = (short)f2bf(u1_[0]); fr_[5] = (short)f2bf(u1_[1]);    \
            fr_[6] = (short)f2bf(u1_[2]); fr_[7] = (short)f2bf(u1_[3]);    \
            FR = fr_;                                                      \
        }
        LOADA(A00, 0)
        LOADA(A01, 32)
        LOADA(A10, 16 * DIMS)
        LOADA(A11, 16 * DIMS + 32)
#undef LOADA
    }

    const char*  pbase = (const char*)ws + 4096 + lane * 16;  // + kt*2048 (+1024 for h=1)
    const float* nhc2  = ws + 4 + r15;                        // + kt*16

    float bv00 = -3.4e38f, bv01 = -3.4e38f, bv02 = -3.4e38f, bv03 = -3.4e38f;
    float bv10 = -3.4e38f, bv11 = -3.4e38f, bv12 = -3.4e38f, bv13 = -3.4e38f;
    int   bk00 = 0, bk01 = 0, bk02 = 0, bk03 = 0;
    int   bk10 = 0, bk11 = 0, bk12 = 0, bk13 = 0;

#define LOADB(KT, B0, B1, IC)                                              \
    {                                                                      \
        int kk_ = (KT) & 31;                                               \
        const char* bb_ = pbase + kk_ * 2048;                              \
        B0 = *(const short8*)bb_;                                          \
        B1 = *(const short8*)(bb_ + 1024);                                 \
        IC = nhc2[kk_ * 16];                                               \
    }

#define BODY(KT, B0, B1, IC)                                               \
    {                                                                      \
        const int krow_ = (KT) * 16 + r15;                                 \
        f32x4 init_ = {IC, IC, IC, IC};                                    \
        f32x4 a0_ = __builtin_amdgcn_mfma_f32_16x16x32_bf16(A00, B0, init_, 0, 0, 0); \
        a0_       = __builtin_amdgcn_mfma_f32_16x16x32_bf16(A01, B1, a0_,  0, 0, 0);  \
        f32x4 a1_ = __builtin_amdgcn_mfma_f32_16x16x32_bf16(A10, B0, init_, 0, 0, 0); \
        a1_       = __builtin_amdgcn_mfma_f32_16x16x32_bf16(A11, B1, a1_,  0, 0, 0);  \
        if (a0_[0] > bv00) { bv00 = a0_[0]; bk00 = krow_; }                \
        if (a0_[1] > bv01) { bv01 = a0_[1]; bk01 = krow_; }                \
        if (a0_[2] > bv02) { bv02 = a0_[2]; bk02 = krow_; }                \
        if (a0_[3] > bv03) { bv03 = a0_[3]; bk03 = krow_; }                \
        if (a1_[0] > bv10) { bv10 = a1_[0]; bk10 = krow_; }                \
        if (a1_[1] > bv11) { bv11 = a1_[1]; bk11 = krow_; }                \
        if (a1_[2] > bv12) { bv12 = a1_[2]; bk12 = krow_; }                \
        if (a1_[3] > bv13) { bv13 = a1_[3]; bk13 = krow_; }                \
    }

    // ---- score all 512 codebook entries: 32 k-tiles, register double-buffer
    short8 c0, c1, n0, n1;
    float icc, icn;
    LOADB(0, c0, c1, icc)
    for (int kt = 0; kt < 32; kt += 2) {
        LOADB(kt + 1, n0, n1, icn)        // prefetch odd tile
        BODY(kt, c0, c1, icc)             // consume even tile
        LOADB(kt + 2, c0, c1, icc)        // prefetch next even (wraps at 32)
        BODY(kt + 1, n0, n1, icn)         // consume odd tile
    }
#undef LOADB
#undef BODY

    // ---- argmax reduce across the 16 lanes of each row-group (k dimension)
#define RED(BV, BK, M)                                                     \
    {                                                                      \
        float ov_ = __shfl_xor(BV, M, 64);                                 \
        int   ok_ = __shfl_xor(BK, M, 64);                                 \
        if (ov_ > BV || (ov_ == BV && ok_ < BK)) { BV = ov_; BK = ok_; }   \
    }
#pragma unroll
    for (int st = 0; st < 4; ++st) {
        const int m = 1 << st;
        RED(bv00, bk00, m) RED(bv01, bk01, m) RED(bv02, bk02, m) RED(bv03, bk03, m)
        RED(bv10, bk10, m) RED(bv11, bk11, m) RED(bv12, bk12, m) RED(bv13, bk13, m)
    }
#undef RED
    // every lane in group g now holds idx for rows g*4+j (j=0..3) of each tile

    // ---- epilogue: gather codebook rows (fp32), write out, accumulate loss
    const int orow = lane >> 2;        // 0..15: row within tile; orow>>2 == g
    const int cseg = lane & 3;         // 16-float column segment
    const int j2   = orow & 3;
    int idx0 = bk00;
    if (j2 == 1) idx0 = bk01;
    if (j2 == 2) idx0 = bk02;
    if (j2 == 3) idx0 = bk03;
    int idx1 = bk10;
    if (j2 == 1) idx1 = bk11;
    if (j2 == 2) idx1 = bk12;
    if (j2 == 3) idx1 = bk13;

    float lsum = 0.0f;
#define EPI(IDX, TOFF)                                                     \
    {                                                                      \
        const long row_ = rowbase + (TOFF) + orow;                         \
        const f4* cq_ = (const f4*)(cb + (long)(IDX) * DIMS + cseg * 16);  \
        const f4* xr_ = (const f4*)(x + row_ * DIMS + cseg * 16);          \
        f4* op_      = (f4*)(out + row_ * DIMS + cseg * 16);               \
        _Pragma("unroll")                                                  \
        for (int u = 0; u < 4; ++u) {                                      \
            f4 q_ = cq_[u];                                                \
            f4 xv_ = xr_[u];                                               \
            op_[u] = q_;                                                   \
            f4 d_ = q_ - xv_;                                              \
            lsum += d_[0]*d_[0] + d_[1]*d_[1] + d_[2]*d_[2] + d_[3]*d_[3]; \
        }                                                                  \
    }
    EPI(idx0, 0)
    EPI(idx1, 16)
#undef EPI

    // ---- loss: wave reduce -> WG reduce -> one atomic per WG -> last WG writes
#pragma unroll
    for (int s = 0; s < 6; ++s) lsum += __shfl_xor(lsum, 1 << s, 64);
    __shared__ float wsum[4];
    if (lane == 0) wsum[wid] = lsum;
    __syncthreads();
    if (threadIdx.x == 0) {
        float tot = wsum[0] + wsum[1] + wsum[2] + wsum[3];
        atomicAdd(ws, tot);
        __threadfence();
        unsigned int ticket = atomicAdd((unsigned int*)ws + 1, 1u);
        if (ticket == MAIN_WGS - 1) {
            float total = atomicAdd(ws, 0.0f);   // coherent read of final sum
            out[OUT_Q] = 1.25f * total / 8388608.0f;
        }
    }
}

extern "C" void kernel_launch(void* const* d_in, const int* in_sizes, int n_in,
                              void* d_out, int out_size, void* d_ws, size_t ws_size,
                              hipStream_t stream) {
    const float* x  = (const float*)d_in[0];
    const float* cb = (const float*)d_in[1];
    float* out = (float*)d_out;
    float* ws  = (float*)d_ws;
    vq_prep<<<18, 256, 0, stream>>>(cb, ws);
    vq_main<<<MAIN_WGS, 256, 0, stream>>>(x, cb, out, ws);
}

// Round 4
// 44.154 us; speedup vs baseline: 2.8557x; 1.9101x over previous
//
#include <hip/hip_runtime.h>

#define DIMS 64
#define KCB 512
#define OUT_Q 8388608   // 32*64*64*64
#define MAIN_WGS 1024

typedef float f32x4 __attribute__((ext_vector_type(4)));
typedef float f4    __attribute__((ext_vector_type(4)));
typedef short short8 __attribute__((ext_vector_type(8)));

// ws layout (bytes):
//   [0..4096)     float  per-WG partial loss sums [1024]
//   [4096..6144)  float  neg_half_c2[512]  (= -0.5*||c_k||^2)   (float idx 1024+)
//   [6144..71680) bf16   codebook packed in MFMA B-fragment order:
//                        byte = 6144 + kt*2048 + h*1024 + lane*16 + i*2
//                        holds cb[kt*16 + (lane&15)][h*32 + (lane>>4)*8 + i]

static __device__ __forceinline__ unsigned int f2bf(float f) {
    unsigned int u = __float_as_uint(f);
    unsigned int r = u + 0x7FFFu + ((u >> 16) & 1u);   // RNE
    return r >> 16;
}

__global__ void vq_prep(const float* __restrict__ cb, float* __restrict__ ws) {
    int t = blockIdx.x * blockDim.x + threadIdx.x;   // 0..4607
    if (t < 4096) {
        // pack one 16-byte B-fragment slice
        int kt = t >> 7, rest = t & 127;
        int h = rest >> 6, l = rest & 63;
        int row = kt * 16 + (l & 15);
        int col = h * 32 + ((l >> 4) & 3) * 8;
        const f4* p = (const f4*)(cb + row * DIMS + col);
        f4 u0 = p[0], u1 = p[1];
        unsigned int* dst = (unsigned int*)((char*)ws + 6144 + kt * 2048 + h * 1024 + l * 16);
        dst[0] = (f2bf(u0[1]) << 16) | f2bf(u0[0]);
        dst[1] = (f2bf(u0[3]) << 16) | f2bf(u0[2]);
        dst[2] = (f2bf(u1[1]) << 16) | f2bf(u1[0]);
        dst[3] = (f2bf(u1[3]) << 16) | f2bf(u1[2]);
    } else if (t < 4096 + KCB) {
        int r = t - 4096;
        const f4* p = (const f4*)(cb + r * DIMS);
        float s = 0.0f;
#pragma unroll
        for (int i = 0; i < DIMS / 4; ++i) {
            f4 v = p[i];
            s += v[0]*v[0] + v[1]*v[1] + v[2]*v[2] + v[3]*v[3];
        }
        ws[1024 + r] = -0.5f * s;
    }
}

__global__ __launch_bounds__(256, 4) void vq_main(const float* __restrict__ x,
                                                  const float* __restrict__ cb,
                                                  float* __restrict__ out,
                                                  float* __restrict__ ws) {
    const int lane = threadIdx.x & 63;
    const int wid  = threadIdx.x >> 6;
    const int iter = blockIdx.x * 4 + wid;        // 0..4095
    const long rowbase = (long)iter * 32;         // 32 x-rows per wave (2 tiles)
    const int r15 = lane & 15;
    const int g   = lane >> 4;

    // ---- A fragments (named, no arrays): lane holds A[row=r15][k=g*8+i(+32h)]
    short8 A00, A01, A10, A11;
    {
        const float* xa = x + (rowbase + r15) * DIMS + g * 8;
#define LOADA(FR, OFF)                                                     \
        {                                                                  \
            const f4* p_ = (const f4*)(xa + (OFF));                        \
            f4 u0_ = p_[0], u1_ = p_[1];                                   \
            short8 fr_;                                                    \
            fr_[0] = (short)f2bf(u0_[0]); fr_[1] = (short)f2bf(u0_[1]);    \
            fr_[2] = (short)f2bf(u0_[2]); fr_[3] = (short)f2bf(u0_[3]);    \
            fr_[4] = (short)f2bf(u1_[0]); fr_[5] = (short)f2bf(u1_[1]);    \
            fr_[6] = (short)f2bf(u1_[2]); fr_[7] = (short)f2bf(u1_[3]);    \
            FR = fr_;                                                      \
        }
        LOADA(A00, 0)
        LOADA(A01, 32)
        LOADA(A10, 16 * DIMS)
        LOADA(A11, 16 * DIMS + 32)
#undef LOADA
    }

    const char*  pbase = (const char*)ws + 6144 + lane * 16;  // + kt*2048 (+1024 for h=1)
    const float* nhc2  = ws + 1024 + r15;                     // + kt*16

    float bv00 = -3.4e38f, bv01 = -3.4e38f, bv02 = -3.4e38f, bv03 = -3.4e38f;
    float bv10 = -3.4e38f, bv11 = -3.4e38f, bv12 = -3.4e38f, bv13 = -3.4e38f;
    int   bk00 = 0, bk01 = 0, bk02 = 0, bk03 = 0;
    int   bk10 = 0, bk11 = 0, bk12 = 0, bk13 = 0;

#define LOADB(KT, B0, B1, IC)                                              \
    {                                                                      \
        int kk_ = (KT) & 31;                                               \
        const char* bb_ = pbase + kk_ * 2048;                              \
        B0 = *(const short8*)bb_;                                          \
        B1 = *(const short8*)(bb_ + 1024);                                 \
        IC = nhc2[kk_ * 16];                                               \
    }

#define BODY(KT, B0, B1, IC)                                               \
    {                                                                      \
        const int krow_ = (KT) * 16 + r15;                                 \
        f32x4 init_ = {IC, IC, IC, IC};                                    \
        f32x4 a0_ = __builtin_amdgcn_mfma_f32_16x16x32_bf16(A00, B0, init_, 0, 0, 0); \
        a0_       = __builtin_amdgcn_mfma_f32_16x16x32_bf16(A01, B1, a0_,  0, 0, 0);  \
        f32x4 a1_ = __builtin_amdgcn_mfma_f32_16x16x32_bf16(A10, B0, init_, 0, 0, 0); \
        a1_       = __builtin_amdgcn_mfma_f32_16x16x32_bf16(A11, B1, a1_,  0, 0, 0);  \
        if (a0_[0] > bv00) { bv00 = a0_[0]; bk00 = krow_; }                \
        if (a0_[1] > bv01) { bv01 = a0_[1]; bk01 = krow_; }                \
        if (a0_[2] > bv02) { bv02 = a0_[2]; bk02 = krow_; }                \
        if (a0_[3] > bv03) { bv03 = a0_[3]; bk03 = krow_; }                \
        if (a1_[0] > bv10) { bv10 = a1_[0]; bk10 = krow_; }                \
        if (a1_[1] > bv11) { bv11 = a1_[1]; bk11 = krow_; }                \
        if (a1_[2] > bv12) { bv12 = a1_[2]; bk12 = krow_; }                \
        if (a1_[3] > bv13) { bv13 = a1_[3]; bk13 = krow_; }                \
    }

    // ---- score all 512 codebook entries: 32 k-tiles, register double-buffer
    short8 c0, c1, n0, n1;
    float icc, icn;
    LOADB(0, c0, c1, icc)
    for (int kt = 0; kt < 32; kt += 2) {
        LOADB(kt + 1, n0, n1, icn)        // prefetch odd tile
        BODY(kt, c0, c1, icc)             // consume even tile
        LOADB(kt + 2, c0, c1, icc)        // prefetch next even (wraps at 32)
        BODY(kt + 1, n0, n1, icn)         // consume odd tile
    }
#undef LOADB
#undef BODY

    // ---- argmax reduce across the 16 lanes of each row-group (k dimension)
#define RED(BV, BK, M)                                                     \
    {                                                                      \
        float ov_ = __shfl_xor(BV, M, 64);                                 \
        int   ok_ = __shfl_xor(BK, M, 64);                                 \
        if (ov_ > BV || (ov_ == BV && ok_ < BK)) { BV = ov_; BK = ok_; }   \
    }
#pragma unroll
    for (int st = 0; st < 4; ++st) {
        const int m = 1 << st;
        RED(bv00, bk00, m) RED(bv01, bk01, m) RED(bv02, bk02, m) RED(bv03, bk03, m)
        RED(bv10, bk10, m) RED(bv11, bk11, m) RED(bv12, bk12, m) RED(bv13, bk13, m)
    }
#undef RED
    // every lane in group g now holds idx for rows g*4+j (j=0..3) of each tile

    // ---- epilogue: gather codebook rows (fp32), write out, accumulate loss
    const int orow = lane >> 2;        // 0..15: row within tile; orow>>2 == g
    const int cseg = lane & 3;         // 16-float column segment
    const int j2   = orow & 3;
    int idx0 = bk00;
    if (j2 == 1) idx0 = bk01;
    if (j2 == 2) idx0 = bk02;
    if (j2 == 3) idx0 = bk03;
    int idx1 = bk10;
    if (j2 == 1) idx1 = bk11;
    if (j2 == 2) idx1 = bk12;
    if (j2 == 3) idx1 = bk13;

    float lsum = 0.0f;
#define EPI(IDX, TOFF)                                                     \
    {                                                                      \
        const long row_ = rowbase + (TOFF) + orow;                         \
        const f4* cq_ = (const f4*)(cb + (long)(IDX) * DIMS + cseg * 16);  \
        const f4* xr_ = (const f4*)(x + row_ * DIMS + cseg * 16);          \
        f4* op_      = (f4*)(out + row_ * DIMS + cseg * 16);               \
        _Pragma("unroll")                                                  \
        for (int u = 0; u < 4; ++u) {                                      \
            f4 q_ = cq_[u];                                                \
            f4 xv_ = xr_[u];                                               \
            op_[u] = q_;                                                   \
            f4 d_ = q_ - xv_;                                              \
            lsum += d_[0]*d_[0] + d_[1]*d_[1] + d_[2]*d_[2] + d_[3]*d_[3]; \
        }                                                                  \
    }
    EPI(idx0, 0)
    EPI(idx1, 16)
#undef EPI

    // ---- loss: wave reduce -> WG reduce -> ONE plain store per WG (no atomics)
#pragma unroll
    for (int s = 0; s < 6; ++s) lsum += __shfl_xor(lsum, 1 << s, 64);
    __shared__ float wsum[4];
    if (lane == 0) wsum[wid] = lsum;
    __syncthreads();
    if (threadIdx.x == 0) {
        ws[blockIdx.x] = wsum[0] + wsum[1] + wsum[2] + wsum[3];
    }
}

__global__ __launch_bounds__(256) void vq_final(const float* __restrict__ ws,
                                                float* __restrict__ out) {
    const int t = threadIdx.x;
    float s = ws[t] + ws[t + 256] + ws[t + 512] + ws[t + 768];
#pragma unroll
    for (int st = 0; st < 6; ++st) s += __shfl_xor(s, 1 << st, 64);
    __shared__ float wsum[4];
    if ((t & 63) == 0) wsum[t >> 6] = s;
    __syncthreads();
    if (t == 0) {
        float total = wsum[0] + wsum[1] + wsum[2] + wsum[3];
        out[OUT_Q] = 1.25f * total / 8388608.0f;
    }
}

extern "C" void kernel_launch(void* const* d_in, const int* in_sizes, int n_in,
                              void* d_out, int out_size, void* d_ws, size_t ws_size,
                              hipStream_t stream) {
    const float* x  = (const float*)d_in[0];
    const float* cb = (const float*)d_in[1];
    float* out = (float*)d_out;
    float* ws  = (float*)d_ws;
    vq_prep<<<18, 256, 0, stream>>>(cb, ws);
    vq_main<<<MAIN_WGS, 256, 0, stream>>>(x, cb, out, ws);
    vq_final<<<1, 256, 0, stream>>>(ws, out);
}

// Round 5
// 34.211 us; speedup vs baseline: 3.6857x; 1.2906x over previous
//
#include <hip/hip_runtime.h>

#define DIMS 64
#define KCB 512
#define OUT_Q 8388608   // 32*64*64*64
#define MAIN_WGS 512

typedef float f32x4 __attribute__((ext_vector_type(4)));
typedef float f4    __attribute__((ext_vector_type(4)));
typedef short short8 __attribute__((ext_vector_type(8)));

// ws layout:
//   float [0..512)      per-WG partial loss sums
//   float [512..1024)   neg_half_c2[512]  (= -0.5*||c_k||^2)
//   byte  [4096..69632) bf16 codebook packed in MFMA B-fragment order:
//                       byte = 4096 + kt*2048 + h*1024 + lane*16 + i*2
//                       holds cb[kt*16 + (lane&15)][h*32 + (lane>>4)*8 + i]

static __device__ __forceinline__ unsigned int f2bf(float f) {
    unsigned int u = __float_as_uint(f);
    unsigned int r = u + 0x7FFFu + ((u >> 16) & 1u);   // RNE
    return r >> 16;
}

__global__ void vq_prep(const float* __restrict__ cb, float* __restrict__ ws) {
    int t = blockIdx.x * blockDim.x + threadIdx.x;   // 0..4607
    if (t < 4096) {
        // pack one 16-byte B-fragment slice
        int kt = t >> 7, rest = t & 127;
        int h = rest >> 6, l = rest & 63;
        int row = kt * 16 + (l & 15);
        int col = h * 32 + ((l >> 4) & 3) * 8;
        const f4* p = (const f4*)(cb + row * DIMS + col);
        f4 u0 = p[0], u1 = p[1];
        unsigned int* dst = (unsigned int*)((char*)ws + 4096 + kt * 2048 + h * 1024 + l * 16);
        dst[0] = (f2bf(u0[1]) << 16) | f2bf(u0[0]);
        dst[1] = (f2bf(u0[3]) << 16) | f2bf(u0[2]);
        dst[2] = (f2bf(u1[1]) << 16) | f2bf(u1[0]);
        dst[3] = (f2bf(u1[3]) << 16) | f2bf(u1[2]);
    } else if (t < 4096 + KCB) {
        int r = t - 4096;
        const f4* p = (const f4*)(cb + r * DIMS);
        float s = 0.0f;
#pragma unroll
        for (int i = 0; i < DIMS / 4; ++i) {
            f4 v = p[i];
            s += v[0]*v[0] + v[1]*v[1] + v[2]*v[2] + v[3]*v[3];
        }
        ws[512 + r] = -0.5f * s;
    }
}

__global__ __launch_bounds__(512, 4) void vq_main(const float* __restrict__ x,
                                                  const float* __restrict__ cb,
                                                  float* __restrict__ out,
                                                  float* __restrict__ ws) {
    __shared__ f4 lds_b4[4096];   // 64 KiB packed bf16 codebook (B-fragment order)

    const int tid  = threadIdx.x;
    const int lane = tid & 63;
    const int wid  = tid >> 6;
    const int wave = blockIdx.x * 8 + wid;        // 0..4095
    const long rowbase = (long)wave * 32;         // 32 x-rows per wave (2 tiles)
    const int r15 = lane & 15;
    const int g   = lane >> 4;

    // ---- stage packed codebook: 8 rounds x 512 threads x 16B = 64 KiB
    {
        const f4* src = (const f4*)((const char*)ws + 4096);
#pragma unroll
        for (int r = 0; r < 8; ++r)
            lds_b4[r * 512 + tid] = src[r * 512 + tid];
    }

    // ---- norms into registers: lane holds n_j = nhc2[j*64 + lane]
    const float* nbase = ws + 512;
    float n0 = nbase[lane], n1 = nbase[64 + lane], n2 = nbase[128 + lane],
          n3 = nbase[192 + lane], n4 = nbase[256 + lane], n5 = nbase[320 + lane],
          n6 = nbase[384 + lane], n7 = nbase[448 + lane];

    // ---- A fragments (named): lane holds A[row=r15][k=g*8+i(+32h)]
    short8 A00, A01, A10, A11;
    {
        const float* xa = x + (rowbase + r15) * DIMS + g * 8;
#define LOADA(FR, OFF)                                                         \
        {                                                                      \
            const f4* p_ = (const f4*)(xa + (OFF));                            \
            f4 a_ = p_[0], b_ = p_[1];                                         \
            union { unsigned int u[4]; short8 s; } q_;                         \
            asm("v_cvt_pk_bf16_f32 %0, %1, %2" : "=v"(q_.u[0]) : "v"(a_[0]), "v"(a_[1])); \
            asm("v_cvt_pk_bf16_f32 %0, %1, %2" : "=v"(q_.u[1]) : "v"(a_[2]), "v"(a_[3])); \
            asm("v_cvt_pk_bf16_f32 %0, %1, %2" : "=v"(q_.u[2]) : "v"(b_[0]), "v"(b_[1])); \
            asm("v_cvt_pk_bf16_f32 %0, %1, %2" : "=v"(q_.u[3]) : "v"(b_[2]), "v"(b_[3])); \
            FR = q_.s;                                                         \
        }
        LOADA(A00, 0)
        LOADA(A01, 32)
        LOADA(A10, 16 * DIMS)
        LOADA(A11, 16 * DIMS + 32)
#undef LOADA
    }

    __syncthreads();   // LDS codebook ready

    // ---- mantissa-packed argmax state (low 9 bits of score carry k)
    float bv00 = -3.4e38f, bv01 = -3.4e38f, bv02 = -3.4e38f, bv03 = -3.4e38f;
    float bv10 = -3.4e38f, bv11 = -3.4e38f, bv12 = -3.4e38f, bv13 = -3.4e38f;

    const char* ldsb = (const char*)lds_b4;
    const int laneoff = lane * 16;

#define NSEL(KT) ((KT>>2)==0?n0:(KT>>2)==1?n1:(KT>>2)==2?n2:(KT>>2)==3?n3: \
                  (KT>>2)==4?n4:(KT>>2)==5?n5:(KT>>2)==6?n6:n7)
#define PKMAX(BV, S)                                                           \
    BV = fmaxf(BV, __uint_as_float((__float_as_uint(S) & 0xFFFFFE00u) | kr));

#pragma unroll
    for (int kt = 0; kt < 32; ++kt) {
        short8 b0 = *(const short8*)(ldsb + kt * 2048 + laneoff);
        short8 b1 = *(const short8*)(ldsb + kt * 2048 + 1024 + laneoff);
        float ic = __shfl(NSEL(kt), ((kt & 3) << 4) + r15, 64);
        f32x4 init = {ic, ic, ic, ic};
        f32x4 a0 = __builtin_amdgcn_mfma_f32_16x16x32_bf16(A00, b0, init, 0, 0, 0);
        a0       = __builtin_amdgcn_mfma_f32_16x16x32_bf16(A01, b1, a0,  0, 0, 0);
        f32x4 a1 = __builtin_amdgcn_mfma_f32_16x16x32_bf16(A10, b0, init, 0, 0, 0);
        a1       = __builtin_amdgcn_mfma_f32_16x16x32_bf16(A11, b1, a1,  0, 0, 0);
        const unsigned int kr = (unsigned int)(kt * 16 + r15);
        PKMAX(bv00, a0[0]) PKMAX(bv01, a0[1]) PKMAX(bv02, a0[2]) PKMAX(bv03, a0[3])
        PKMAX(bv10, a1[0]) PKMAX(bv11, a1[1]) PKMAX(bv12, a1[2]) PKMAX(bv13, a1[3])
    }
#undef PKMAX
#undef NSEL

    // ---- argmax reduce across the 16 lanes of each row-group (k dimension)
#pragma unroll
    for (int st = 0; st < 4; ++st) {
        const int m = 1 << st;
        bv00 = fmaxf(bv00, __shfl_xor(bv00, m, 64));
        bv01 = fmaxf(bv01, __shfl_xor(bv01, m, 64));
        bv02 = fmaxf(bv02, __shfl_xor(bv02, m, 64));
        bv03 = fmaxf(bv03, __shfl_xor(bv03, m, 64));
        bv10 = fmaxf(bv10, __shfl_xor(bv10, m, 64));
        bv11 = fmaxf(bv11, __shfl_xor(bv11, m, 64));
        bv12 = fmaxf(bv12, __shfl_xor(bv12, m, 64));
        bv13 = fmaxf(bv13, __shfl_xor(bv13, m, 64));
    }

    // ---- epilogue: gather codebook rows (fp32), write out, accumulate loss
    const int orow = lane >> 2;        // 0..15: row within tile; orow>>2 == g
    const int cseg = lane & 3;         // 16-float column segment
    const int j2   = orow & 3;
    int idx0 = (int)(__float_as_uint(j2 == 0 ? bv00 : j2 == 1 ? bv01 : j2 == 2 ? bv02 : bv03) & 511u);
    int idx1 = (int)(__float_as_uint(j2 == 0 ? bv10 : j2 == 1 ? bv11 : j2 == 2 ? bv12 : bv13) & 511u);

    float lsum = 0.0f;
#define EPI(IDX, TOFF)                                                     \
    {                                                                      \
        const long row_ = rowbase + (TOFF) + orow;                         \
        const f4* cq_ = (const f4*)(cb + (long)(IDX) * DIMS + cseg * 16);  \
        const f4* xr_ = (const f4*)(x + row_ * DIMS + cseg * 16);          \
        f4* op_      = (f4*)(out + row_ * DIMS + cseg * 16);               \
        _Pragma("unroll")                                                  \
        for (int u = 0; u < 4; ++u) {                                      \
            f4 q_ = cq_[u];                                                \
            f4 xv_ = xr_[u];                                               \
            op_[u] = q_;                                                   \
            f4 d_ = q_ - xv_;                                              \
            lsum += d_[0]*d_[0] + d_[1]*d_[1] + d_[2]*d_[2] + d_[3]*d_[3]; \
        }                                                                  \
    }
    EPI(idx0, 0)
    EPI(idx1, 16)
#undef EPI

    // ---- loss: wave reduce -> per-WG reduce via LDS reuse -> one plain store
#pragma unroll
    for (int s = 0; s < 6; ++s) lsum += __shfl_xor(lsum, 1 << s, 64);
    __syncthreads();                   // everyone done reading lds_b4
    float* lsred = (float*)lds_b4;
    if (lane == 0) lsred[wid] = lsum;
    __syncthreads();
    if (tid == 0) {
        ws[blockIdx.x] = lsred[0] + lsred[1] + lsred[2] + lsred[3]
                       + lsred[4] + lsred[5] + lsred[6] + lsred[7];
    }
}

__global__ __launch_bounds__(256) void vq_final(const float* __restrict__ ws,
                                                float* __restrict__ out) {
    const int t = threadIdx.x;
    float s = ws[t] + ws[t + 256];
#pragma unroll
    for (int st = 0; st < 6; ++st) s += __shfl_xor(s, 1 << st, 64);
    __shared__ float w2[4];
    if ((t & 63) == 0) w2[t >> 6] = s;
    __syncthreads();
    if (t == 0) {
        float total = w2[0] + w2[1] + w2[2] + w2[3];
        out[OUT_Q] = 1.25f * total / 8388608.0f;
    }
}

extern "C" void kernel_launch(void* const* d_in, const int* in_sizes, int n_in,
                              void* d_out, int out_size, void* d_ws, size_t ws_size,
                              hipStream_t stream) {
    const float* x  = (const float*)d_in[0];
    const float* cb = (const float*)d_in[1];
    float* out = (float*)d_out;
    float* ws  = (float*)d_ws;
    vq_prep<<<18, 256, 0, stream>>>(cb, ws);
    vq_main<<<MAIN_WGS, 512, 0, stream>>>(x, cb, out, ws);
    vq_final<<<1, 256, 0, stream>>>(ws, out);
}

// Round 6
// 31.531 us; speedup vs baseline: 3.9989x; 1.0850x over previous
//
#include <hip/hip_runtime.h>

#define DIMS 64
#define KCB 512
#define OUT_Q 8388608   // 32*64*64*64
#define MAIN_WGS 512

typedef float f32x4 __attribute__((ext_vector_type(4)));
typedef float f4    __attribute__((ext_vector_type(4)));
typedef short short8 __attribute__((ext_vector_type(8)));

// ws layout:
//   float [0..512)      per-WG partial loss sums
//   float [512..1024)   neg_half_c2[512]  (= -0.5*||c_k||^2)
//   byte  [4096..69632) bf16 codebook packed in MFMA B-fragment order:
//                       byte = 4096 + kt*2048 + h*1024 + l*16 + i*2
//                       holds cb[kt*16 + (l&15)][h*32 + (l>>4)*8 + i]

static __device__ __forceinline__ unsigned int f2bf(float f) {
    unsigned int u = __float_as_uint(f);
    unsigned int r = u + 0x7FFFu + ((u >> 16) & 1u);   // RNE
    return r >> 16;
}

__global__ void vq_prep(const float* __restrict__ cb, float* __restrict__ ws) {
    int t = blockIdx.x * blockDim.x + threadIdx.x;   // 0..4607
    if (t < 4096) {
        // pack one 16-byte B-fragment slice
        int kt = t >> 7, rest = t & 127;
        int h = rest >> 6, l = rest & 63;
        int row = kt * 16 + (l & 15);
        int col = h * 32 + ((l >> 4) & 3) * 8;
        const f4* p = (const f4*)(cb + row * DIMS + col);
        f4 u0 = p[0], u1 = p[1];
        unsigned int* dst = (unsigned int*)((char*)ws + 4096 + kt * 2048 + h * 1024 + l * 16);
        dst[0] = (f2bf(u0[1]) << 16) | f2bf(u0[0]);
        dst[1] = (f2bf(u0[3]) << 16) | f2bf(u0[2]);
        dst[2] = (f2bf(u1[1]) << 16) | f2bf(u1[0]);
        dst[3] = (f2bf(u1[3]) << 16) | f2bf(u1[2]);
    } else if (t < 4096 + KCB) {
        int r = t - 4096;
        const f4* p = (const f4*)(cb + r * DIMS);
        float s = 0.0f;
#pragma unroll
        for (int i = 0; i < DIMS / 4; ++i) {
            f4 v = p[i];
            s += v[0]*v[0] + v[1]*v[1] + v[2]*v[2] + v[3]*v[3];
        }
        ws[512 + r] = -0.5f * s;
    }
}

__global__ __launch_bounds__(512, 4) void vq_main(const float* __restrict__ x,
                                                  const float* __restrict__ cb,
                                                  float* __restrict__ out,
                                                  float* __restrict__ ws) {
    __shared__ char lds[66560];   // 64 KiB packed codebook + 2 KiB norms + pad

    const int tid  = threadIdx.x;
    const int lane = tid & 63;
    const int wid  = tid >> 6;
    const int wave = blockIdx.x * 8 + wid;        // 0..4095
    const long rowbase = (long)wave * 32;         // 32 x-rows per wave (2 tiles)
    const int r15 = lane & 15;
    const int g   = lane >> 4;

    // ---- stage packed codebook (64 KiB) + norms (2 KiB) into LDS
    {
        const f4* src = (const f4*)((const char*)ws + 4096);
        f4* ldsv = (f4*)lds;
#pragma unroll
        for (int r = 0; r < 8; ++r)
            ldsv[r * 512 + tid] = src[r * 512 + tid];
        ((float*)(lds + 65536))[tid] = ws[512 + tid];
    }

    // ---- A fragments + fp32 row-norm partials (x touched once, in registers)
    short8 A00, A01, A10, A11;
    float xn0 = 0.0f, xn1 = 0.0f;
    {
        const float* xa = x + (rowbase + r15) * DIMS + g * 8;
#define LOADA(FR, OFF, XN)                                                     \
        {                                                                      \
            const f4* p_ = (const f4*)(xa + (OFF));                            \
            f4 a_ = p_[0], b_ = p_[1];                                         \
            XN += a_[0]*a_[0] + a_[1]*a_[1] + a_[2]*a_[2] + a_[3]*a_[3]        \
                + b_[0]*b_[0] + b_[1]*b_[1] + b_[2]*b_[2] + b_[3]*b_[3];       \
            union { unsigned int u[4]; short8 s; } q_;                         \
            asm("v_cvt_pk_bf16_f32 %0, %1, %2" : "=v"(q_.u[0]) : "v"(a_[0]), "v"(a_[1])); \
            asm("v_cvt_pk_bf16_f32 %0, %1, %2" : "=v"(q_.u[1]) : "v"(a_[2]), "v"(a_[3])); \
            asm("v_cvt_pk_bf16_f32 %0, %1, %2" : "=v"(q_.u[2]) : "v"(b_[0]), "v"(b_[1])); \
            asm("v_cvt_pk_bf16_f32 %0, %1, %2" : "=v"(q_.u[3]) : "v"(b_[2]), "v"(b_[3])); \
            FR = q_.s;                                                         \
        }
        LOADA(A00, 0, xn0)
        LOADA(A01, 32, xn0)
        LOADA(A10, 16 * DIMS, xn1)
        LOADA(A11, 16 * DIMS + 32, xn1)
#undef LOADA
    }
    // full row norms: sum the 4 g-groups (lane keeps ||x_row(r15,tile)||^2)
    xn0 += __shfl_xor(xn0, 16, 64);  xn0 += __shfl_xor(xn0, 32, 64);
    xn1 += __shfl_xor(xn1, 16, 64);  xn1 += __shfl_xor(xn1, 32, 64);

    __syncthreads();   // LDS codebook + norms ready

    // ---- mantissa-packed argmax state (low 9 bits of score carry k)
    float bv00 = -3.4e38f, bv01 = -3.4e38f, bv02 = -3.4e38f, bv03 = -3.4e38f;
    float bv10 = -3.4e38f, bv11 = -3.4e38f, bv12 = -3.4e38f, bv13 = -3.4e38f;

    const char*  ldsb = lds;
    const float* ldsn = (const float*)(lds + 65536);
    const int laneoff = lane * 16;

#define PKMAX(BV, S)                                                           \
    BV = fmaxf(BV, __uint_as_float((__float_as_uint(S) & 0xFFFFFE00u) | kr));

#pragma unroll
    for (int kt = 0; kt < 32; ++kt) {
        short8 b0 = *(const short8*)(ldsb + kt * 2048 + laneoff);
        short8 b1 = *(const short8*)(ldsb + kt * 2048 + 1024 + laneoff);
        float ic = ldsn[kt * 16 + r15];          // conflict-free broadcast read
        f32x4 init = {ic, ic, ic, ic};
        f32x4 a0 = __builtin_amdgcn_mfma_f32_16x16x32_bf16(A00, b0, init, 0, 0, 0);
        a0       = __builtin_amdgcn_mfma_f32_16x16x32_bf16(A01, b1, a0,  0, 0, 0);
        f32x4 a1 = __builtin_amdgcn_mfma_f32_16x16x32_bf16(A10, b0, init, 0, 0, 0);
        a1       = __builtin_amdgcn_mfma_f32_16x16x32_bf16(A11, b1, a1,  0, 0, 0);
        const unsigned int kr = (unsigned int)(kt * 16 + r15);
        PKMAX(bv00, a0[0]) PKMAX(bv01, a0[1]) PKMAX(bv02, a0[2]) PKMAX(bv03, a0[3])
        PKMAX(bv10, a1[0]) PKMAX(bv11, a1[1]) PKMAX(bv12, a1[2]) PKMAX(bv13, a1[3])
    }
#undef PKMAX

    // ---- argmax reduce across the 16 lanes of each row-group (k dimension)
#pragma unroll
    for (int st = 0; st < 4; ++st) {
        const int m = 1 << st;
        bv00 = fmaxf(bv00, __shfl_xor(bv00, m, 64));
        bv01 = fmaxf(bv01, __shfl_xor(bv01, m, 64));
        bv02 = fmaxf(bv02, __shfl_xor(bv02, m, 64));
        bv03 = fmaxf(bv03, __shfl_xor(bv03, m, 64));
        bv10 = fmaxf(bv10, __shfl_xor(bv10, m, 64));
        bv11 = fmaxf(bv11, __shfl_xor(bv11, m, 64));
        bv12 = fmaxf(bv12, __shfl_xor(bv12, m, 64));
        bv13 = fmaxf(bv13, __shfl_xor(bv13, m, 64));
    }

    // ---- epilogue: pure gather -> store (no x re-read)
    const int orow = lane >> 2;        // 0..15: row within tile
    const int cseg = lane & 3;         // 16-float column segment
    const int j2   = orow & 3;
    int idx0 = (int)(__float_as_uint(j2 == 0 ? bv00 : j2 == 1 ? bv01 : j2 == 2 ? bv02 : bv03) & 511u);
    int idx1 = (int)(__float_as_uint(j2 == 0 ? bv10 : j2 == 1 ? bv11 : j2 == 2 ? bv12 : bv13) & 511u);

#define EPI(IDX, TOFF)                                                     \
    {                                                                      \
        const long row_ = rowbase + (TOFF) + orow;                         \
        const f4* cq_ = (const f4*)(cb + (long)(IDX) * DIMS + cseg * 16);  \
        f4* op_      = (f4*)(out + row_ * DIMS + cseg * 16);               \
        _Pragma("unroll")                                                  \
        for (int u = 0; u < 4; ++u) op_[u] = cq_[u];                       \
    }
    EPI(idx0, 0)
    EPI(idx1, 16)
#undef EPI

    // ---- loss from scores: ||q-x||^2 = ||x||^2 - 2*best  (no x re-read)
    float lsum = 0.0f;
    if (g == (r15 >> 2)) {             // this lane's bv row (g*4+j') == its r15 row
        const int jp = r15 & 3;
        float s0 = jp == 0 ? bv00 : jp == 1 ? bv01 : jp == 2 ? bv02 : bv03;
        float s1 = jp == 0 ? bv10 : jp == 1 ? bv11 : jp == 2 ? bv12 : bv13;
        s0 = __uint_as_float(__float_as_uint(s0) & 0xFFFFFE00u);
        s1 = __uint_as_float(__float_as_uint(s1) & 0xFFFFFE00u);
        lsum = (xn0 - 2.0f * s0) + (xn1 - 2.0f * s1);
    }
#pragma unroll
    for (int s = 0; s < 6; ++s) lsum += __shfl_xor(lsum, 1 << s, 64);

    __syncthreads();                   // all waves done reading lds codebook
    float* lsred = (float*)lds;
    if (lane == 0) lsred[wid] = lsum;
    __syncthreads();
    if (tid == 0) {
        ws[blockIdx.x] = lsred[0] + lsred[1] + lsred[2] + lsred[3]
                       + lsred[4] + lsred[5] + lsred[6] + lsred[7];
    }
}

__global__ __launch_bounds__(256) void vq_final(const float* __restrict__ ws,
                                                float* __restrict__ out) {
    const int t = threadIdx.x;
    float s = ws[t] + ws[t + 256];
#pragma unroll
    for (int st = 0; st < 6; ++st) s += __shfl_xor(s, 1 << st, 64);
    __shared__ float w2[4];
    if ((t & 63) == 0) w2[t >> 6] = s;
    __syncthreads();
    if (t == 0) {
        float total = w2[0] + w2[1] + w2[2] + w2[3];
        out[OUT_Q] = 1.25f * total / 8388608.0f;
    }
}

extern "C" void kernel_launch(void* const* d_in, const int* in_sizes, int n_in,
                              void* d_out, int out_size, void* d_ws, size_t ws_size,
                              hipStream_t stream) {
    const float* x  = (const float*)d_in[0];
    const float* cb = (const float*)d_in[1];
    float* out = (float*)d_out;
    float* ws  = (float*)d_ws;
    vq_prep<<<18, 256, 0, stream>>>(cb, ws);
    vq_main<<<MAIN_WGS, 512, 0, stream>>>(x, cb, out, ws);
    vq_final<<<1, 256, 0, stream>>>(ws, out);
}